// Round 9
// baseline (575.338 us; speedup 1.0000x reference)
//
#include <hip/hip_runtime.h>
#include <cmath>

#define B_ 32
#define S_ 1024
#define D_ 256
#define K_ 1024
#define N_ (B_*S_)

// ---- output layout (float elements) ----
#define O_Q     0
#define O_LOSS  8388608
#define O_PERP  8388609
#define O_IDX   8388610
#define O_NW    8421378
#define O_NEW   8683522
#define O_NCS   8945666

// ---- workspace layout (bytes) ----
#define OFF_FH    0ull          // N*256*2 = 16777216 (f16 feats)
#define OFF_WH    16777216ull   // K*256*2 = 524288  (f16 weights)
#define OFF_BW    17301504ull   // K*8
#define OFF_BWF   17309696ull   // K*4
#define OFF_SAMP  17313792ull   // N*8
#define OFF_IDXF  17575936ull   // N*4
#define OFF_ENC   17707008ull   // N*4
#define OFF_CNT   17838080ull   // K*4 (zeroed)
#define OFF_SLOWC 17842176ull   // 64  (zeroed, same memset)
#define OFF_SLOWL 17842240ull   // N*4
#define OFF_LOSSP 17973312ull   // N*8

#define MARGIN 4e-5f

typedef _Float16 f16x8 __attribute__((ext_vector_type(8)));
typedef float    f32x4 __attribute__((ext_vector_type(4)));

// ---------------- fused: LN -> f16 feats  |  ||w||^2 + f16 w -------------
__global__ void k_pre(const float* __restrict__ x, const float* __restrict__ gam,
                      const float* __restrict__ bet, _Float16* __restrict__ fh,
                      const float* __restrict__ w, double* __restrict__ Bw,
                      float* __restrict__ Bwf, _Float16* __restrict__ wh) {
    int lane = threadIdx.x & 63, wv = threadIdx.x >> 6;
    if (blockIdx.x < N_ / 4) {
        int n = blockIdx.x * 4 + wv;
        const float* row = x + (size_t)n * D_;
        double xv[4], gv[4], bv[4];
#pragma unroll
        for (int i = 0; i < 4; i++) {
            int d = lane + 64 * i;
            xv[i] = row[d]; gv[i] = gam[d]; bv[i] = bet[d];
        }
        double s = xv[0] + xv[1] + xv[2] + xv[3];
        for (int m = 32; m > 0; m >>= 1) s += __shfl_xor(s, m, 64);
        double mu = s / 256.0, vs = 0.0;
#pragma unroll
        for (int i = 0; i < 4; i++) { double c = xv[i] - mu; vs += c * c; }
        for (int m = 32; m > 0; m >>= 1) vs += __shfl_xor(vs, m, 64);
        double inv = 1.0 / sqrt(vs / 256.0 + 1e-5);
#pragma unroll
        for (int i = 0; i < 4; i++) {
            int d = lane + 64 * i;
            float ff = (float)((xv[i] - mu) * inv * gv[i] + bv[i]);
            fh[(size_t)n * D_ + d] = (_Float16)ff;
        }
    } else {
        int k = (blockIdx.x - N_ / 4) * 4 + wv;
        double s = 0.0;
#pragma unroll
        for (int i = 0; i < 4; i++) {
            int d = lane + 64 * i;
            float v = w[(size_t)k * D_ + d];
            s += (double)v * (double)v;
            wh[(size_t)k * D_ + d] = (_Float16)v;
        }
        for (int m = 32; m > 0; m >>= 1) s += __shfl_xor(s, m, 64);
        if (lane == 0) { Bw[k] = s; Bwf[k] = (float)s; }
    }
}

// ---------------- Phase 1: barrier-free, LDS-free f16 MFMA full-K sweep ----
// 512 blocks x 64 thr (one wave). Wave = 64 rows x ALL 1024 codes.
// A-frags (64 rows x 256 dims) held in VGPRs; codebook streamed from L2 in
// 32-code chunks; running top-2 in registers; zero __syncthreads.
// Frag loads straight from row-major global: lane reads 16B at
// (row_or_code = base+l15)*256 + kf*32 + g*8  -> touches exactly 16 lines.
__launch_bounds__(64)
__global__ void k_phase1(const _Float16* __restrict__ fh, const _Float16* __restrict__ wh,
                         const float* __restrict__ Bwf, float* __restrict__ pq) {
    const int lane = threadIdx.x;
    const int l15 = lane & 15;
    const int g = lane >> 4;        // 0..3
    const int row0 = blockIdx.x * 64;

    // A fragments: af[fr][kf] covers rows [row0+fr*16, +16) dims [kf*32, +32)
    f16x8 af[4][8];
#pragma unroll
    for (int fr = 0; fr < 4; fr++)
#pragma unroll
        for (int kf = 0; kf < 8; kf++)
            af[fr][kf] = *(const f16x8*)(fh + (size_t)(row0 + fr * 16 + l15) * 256
                                             + kf * 32 + g * 8);

    float rm1[16], rm2[16]; int rc1[16];
#pragma unroll
    for (int i = 0; i < 16; i++) { rm1[i] = 3e38f; rm2[i] = 3e38f; rc1[i] = 0x7fffffff; }

    for (int cb = 0; cb < K_; cb += 32) {
        f16x8 bfr[2][8];
#pragma unroll
        for (int fc = 0; fc < 2; fc++)
#pragma unroll
            for (int kf = 0; kf < 8; kf++)
                bfr[fc][kf] = *(const f16x8*)(wh + (size_t)(cb + fc * 16 + l15) * 256
                                                  + kf * 32 + g * 8);
        f32x4 acc[4][2];
#pragma unroll
        for (int fr = 0; fr < 4; fr++)
#pragma unroll
            for (int fc = 0; fc < 2; fc++) acc[fr][fc] = (f32x4){0.f, 0.f, 0.f, 0.f};
#pragma unroll
        for (int kf = 0; kf < 8; kf++)
#pragma unroll
            for (int fr = 0; fr < 4; fr++)
#pragma unroll
                for (int fc = 0; fc < 2; fc++)
                    acc[fr][fc] = __builtin_amdgcn_mfma_f32_16x16x32_f16(
                        af[fr][kf], bfr[fc][kf], acc[fr][fc], 0, 0, 0);

        float bwv[2];
        bwv[0] = Bwf[cb + l15];
        bwv[1] = Bwf[cb + 16 + l15];
#pragma unroll
        for (int fr = 0; fr < 4; fr++) {
#pragma unroll
            for (int r = 0; r < 4; r++) {
                float m1, m2; int c1;
                {
                    float s0 = fmaf(-2.0f, acc[fr][0][r], bwv[0]);
                    float s1 = fmaf(-2.0f, acc[fr][1][r], bwv[1]);
                    // code idx: cb + fc*16 + l15 ; fc=0 always lower index
                    if (s1 < s0) { m1 = s1; m2 = s0; c1 = cb + 16 + l15; }
                    else         { m1 = s0; m2 = s1; c1 = cb + l15; }
                }
#pragma unroll
                for (int msk = 1; msk <= 8; msk <<= 1) {
                    float om1 = __shfl_xor(m1, msk, 64);
                    float om2 = __shfl_xor(m2, msk, 64);
                    int   oc  = __shfl_xor(c1, msk, 64);
                    if (om1 < m1 || (om1 == m1 && oc < c1)) {
                        m2 = (m1 < om2) ? m1 : om2; m1 = om1; c1 = oc;
                    } else {
                        m2 = (om1 < m2) ? om1 : m2;
                    }
                }
                int sl = fr * 4 + r;
                if (m1 < rm1[sl] || (m1 == rm1[sl] && c1 < rc1[sl])) {
                    rm2[sl] = (rm1[sl] < m2) ? rm1[sl] : m2; rm1[sl] = m1; rc1[sl] = c1;
                } else {
                    rm2[sl] = (m1 < rm2[sl]) ? m1 : rm2[sl];
                }
            }
        }
    }
    // after the xor-butterfly all 16 lanes of a g-group agree; lane l15==0 of
    // each g writes its 16 row-slots (row = row0 + fr*16 + g*4 + r).
    if (l15 == 0) {
        float* m1o = pq;
        float* m2o = pq + N_;
        int*   c1o = (int*)pq + 2 * N_;
#pragma unroll
        for (int fr = 0; fr < 4; fr++)
#pragma unroll
            for (int r = 0; r < 4; r++) {
                int row = row0 + fr * 16 + g * 4 + r;
                m1o[row] = rm1[fr * 4 + r];
                m2o[row] = rm2[fr * 4 + r];
                c1o[row] = rc1[fr * 4 + r];
            }
    }
}

// ---------------- Phase 2: exact f64 verify (single partial now) ----
__global__ void k_phase2(const float* __restrict__ x, const float* __restrict__ gam,
                         const float* __restrict__ bet, const float* __restrict__ w,
                         const double* __restrict__ Bw, const float* __restrict__ pq,
                         double* __restrict__ sampled, int* __restrict__ idxf,
                         unsigned* __restrict__ slowC, int* __restrict__ slowL) {
    int lane = threadIdx.x & 63, wv = threadIdx.x >> 6;
    int n = blockIdx.x * 4 + wv;
    float M1 = pq[n];
    float M2 = pq[N_ + n];
    int   C1 = ((const int*)pq)[2 * N_ + n];
    if (M2 - M1 <= MARGIN) {
        if (lane == 0) { unsigned p = atomicAdd(slowC, 1u); slowL[p] = n; }
        return;
    }
    const float* row = x + (size_t)n * D_;
    double xv[4], gv[4], bv[4];
#pragma unroll
    for (int i = 0; i < 4; i++) {
        int d = lane + 64 * i;
        xv[i] = row[d]; gv[i] = gam[d]; bv[i] = bet[d];
    }
    double s = xv[0] + xv[1] + xv[2] + xv[3];
    for (int m = 32; m > 0; m >>= 1) s += __shfl_xor(s, m, 64);
    double mu = s / 256.0, vs = 0.0;
#pragma unroll
    for (int i = 0; i < 4; i++) { double c = xv[i] - mu; vs += c * c; }
    for (int m = 32; m > 0; m >>= 1) vs += __shfl_xor(vs, m, 64);
    double inv = 1.0 / sqrt(vs / 256.0 + 1e-5);
    double f[4], A = 0.0;
#pragma unroll
    for (int i = 0; i < 4; i++) {
        f[i] = (xv[i] - mu) * inv * gv[i] + bv[i];
        A += f[i] * f[i];
    }
    for (int m = 32; m > 0; m >>= 1) A += __shfl_xor(A, m, 64);

    const float* wr_ = w + (size_t)C1 * D_;
    double ss = 0.0;
#pragma unroll
    for (int i = 0; i < 4; i++) ss += f[i] * (double)wr_[lane + 64 * i];
    for (int m = 32; m > 0; m >>= 1) ss += __shfl_xor(ss, m, 64);
    if (lane == 0) { sampled[n] = (A + Bw[C1]) - 2.0 * ss; idxf[n] = C1; }
}

// ---------------- Slow rows: exact f64 full scan, lanes-over-codes -------------
__launch_bounds__(256)
__global__ void k_slow(const float* __restrict__ x, const float* __restrict__ gam,
                       const float* __restrict__ bet, const float* __restrict__ w,
                       const double* __restrict__ Bw,
                       const int* __restrict__ slowL, const unsigned* __restrict__ slowC,
                       double* __restrict__ sampled, int* __restrict__ idxf) {
    __shared__ double sf[256];
    __shared__ double red8[8];
    __shared__ double bmW[4];
    __shared__ int    bcW[4];
    int tid = threadIdx.x, lane = tid & 63, wv = tid >> 6;
    int cnt = (int)*slowC;
    for (int it = blockIdx.x; it < cnt; it += gridDim.x) {
        int n = slowL[it];
        double xv = x[(size_t)n * D_ + tid];
        double gv = gam[tid], bv = bet[tid];
        double s = xv;
        for (int m = 32; m > 0; m >>= 1) s += __shfl_xor(s, m, 64);
        if (lane == 0) red8[wv] = s;
        __syncthreads();
        double mu = (red8[0] + red8[1] + red8[2] + red8[3]) / 256.0;
        double c = xv - mu;
        double v2 = c * c;
        for (int m = 32; m > 0; m >>= 1) v2 += __shfl_xor(v2, m, 64);
        __syncthreads();
        if (lane == 0) red8[wv] = v2;
        __syncthreads();
        double var = (red8[0] + red8[1] + red8[2] + red8[3]) / 256.0;
        double inv = 1.0 / sqrt(var + 1e-5);
        double f = c * inv * gv + bv;
        double a2 = f * f;
        for (int m = 32; m > 0; m >>= 1) a2 += __shfl_xor(a2, m, 64);
        if (lane == 0) red8[4 + wv] = a2;
        sf[tid] = f;
        __syncthreads();
        double A = red8[4] + red8[5] + red8[6] + red8[7];

        double bm = 1.0e300; int bc = 0x7fffffff;
        for (int r = 0; r < 4; r++) {
            int cc = r * 256 + wv * 64 + lane;
            const float* wr = w + (size_t)cc * D_;
            double acc = 0.0;
#pragma unroll 8
            for (int d4 = 0; d4 < 64; d4++) {
                float4 w4 = *(const float4*)(wr + d4 * 4);
                acc += sf[d4 * 4] * (double)w4.x + sf[d4 * 4 + 1] * (double)w4.y
                     + sf[d4 * 4 + 2] * (double)w4.z + sf[d4 * 4 + 3] * (double)w4.w;
            }
            double dist = (A + Bw[cc]) - 2.0 * acc;
            if (dist < bm) { bm = dist; bc = cc; }
        }
        for (int m = 32; m > 0; m >>= 1) {
            double om = __shfl_xor(bm, m, 64);
            int    oc = __shfl_xor(bc, m, 64);
            if (om < bm || (om == bm && oc < bc)) { bm = om; bc = oc; }
        }
        if (lane == 0) { bmW[wv] = bm; bcW[wv] = bc; }
        __syncthreads();
        if (tid == 0) {
            double M = bmW[0]; int C = bcW[0];
            for (int i = 1; i < 4; i++)
                if (bmW[i] < M || (bmW[i] == M && bcW[i] < C)) { M = bmW[i]; C = bcW[i]; }
            sampled[n] = M; idxf[n] = C;
        }
        __syncthreads();
    }
}

// ---------------- stable argsort per batch row + enc gather -------------
__launch_bounds__(1024)
__global__ void k_sort(const double* __restrict__ sampled, const int* __restrict__ idxf,
                       int* __restrict__ enc) {
    __shared__ double val[1024];
    __shared__ int    sid[1024];
    int b = blockIdx.x, t = threadIdx.x;
    val[t] = sampled[(size_t)b * S_ + t];
    sid[t] = t;
    __syncthreads();
    for (int k = 2; k <= 1024; k <<= 1) {
        for (int j = k >> 1; j > 0; j >>= 1) {
            int p = t ^ j;
            if (p > t) {
                double v0 = val[t], v1 = val[p];
                int i0 = sid[t], i1 = sid[p];
                bool gtv = (v0 > v1) || (v0 == v1 && i0 > i1);
                bool asc = ((t & k) == 0);
                if (asc ? gtv : !gtv) {
                    val[t] = v1; val[p] = v0; sid[t] = i1; sid[p] = i0;
                }
            }
            __syncthreads();
        }
    }
    enc[(size_t)b * S_ + t] = idxf[sid[t]];   // faithful reference flat-index bug
}

// ---------------- gather: quantized out, idx out, counts, per-row loss -------------
__global__ void k_gather(const float* __restrict__ x, const float* __restrict__ w,
                         const int* __restrict__ enc, float* __restrict__ out,
                         unsigned* __restrict__ cnt, double* __restrict__ lossP) {
    int lane = threadIdx.x & 63, wv = threadIdx.x >> 6;
    int n = blockIdx.x * 4 + wv;
    int e = enc[n];
    const float* wr_ = w + (size_t)e * D_;
    const float* xr = x + (size_t)n * D_;
    float* qr = out + O_Q + (size_t)n * D_;
    double ls = 0.0;
#pragma unroll
    for (int i = 0; i < 4; i++) {
        int d = lane + 64 * i;
        float q = wr_[d], xv = xr[d];
        qr[d] = q;
        double df = (double)q - (double)xv;
        ls += df * df;
    }
    for (int m = 32; m > 0; m >>= 1) ls += __shfl_xor(ls, m, 64);
    if (lane == 0) {
        lossP[n] = ls;
        out[O_IDX + n] = (float)e;
        atomicAdd(&cnt[e], 1u);
    }
}

// ---------------- post: dw (enc-scan, no CSR) + new_weight + stats -------------
__launch_bounds__(256)
__global__ void k_post(const unsigned* __restrict__ cnt, const float* __restrict__ ema_cs,
                       const double* __restrict__ lossP, const int* __restrict__ enc,
                       const float* __restrict__ x, const float* __restrict__ ema_w,
                       float* __restrict__ out) {
    __shared__ double redd[24];
    __shared__ int mrows[1024];
    __shared__ int mcnt;
    __shared__ double ntot_s;
    int tid = threadIdx.x;

    double part = 0.0;
    for (int i = tid; i < K_; i += 256)
        part += (double)(0.99f * ema_cs[i] + 0.01f * (float)cnt[i]);
    for (int m = 32; m > 0; m >>= 1) part += __shfl_xor(part, m, 64);
    if ((tid & 63) == 0) redd[tid >> 6] = part;
    __syncthreads();
    if (tid == 0) ntot_s = redd[0] + redd[1] + redd[2] + redd[3];
    __syncthreads();
    double ntot = ntot_s;

    if (blockIdx.x < K_) {
        int k = blockIdx.x;
        float cs0 = 0.99f * ema_cs[k] + 0.01f * (float)cnt[k];
        double csf = ((double)cs0 + 1e-5) / (ntot + 1024.0 * 1e-5) * ntot;
        float acc = 0.0f;
        if (tid == 0) mcnt = 0;
        __syncthreads();
        for (int tile = 0; tile < 32; tile++) {
            for (int j = tid; j < 1024; j += 256) {
                int r = tile * 1024 + j;
                if (enc[r] == k) { int p = atomicAdd(&mcnt, 1); mrows[p] = r; }
            }
            __syncthreads();
            int mc = mcnt;
            for (int j = 0; j < mc; j++) acc += x[(size_t)mrows[j] * D_ + tid];
            __syncthreads();
            if (tid == 0) mcnt = 0;
            __syncthreads();
        }
        size_t idx = (size_t)k * D_ + tid;
        float ne = 0.99f * ema_w[idx] + 0.01f * acc;
        out[O_NEW + idx] = ne;
        out[O_NW + idx] = ne / (float)csf;
    } else {
        for (int i = tid; i < K_; i += 256) {
            float cs0 = 0.99f * ema_cs[i] + 0.01f * (float)cnt[i];
            double c2 = ((double)cs0 + 1e-5) / (ntot + 1024.0 * 1e-5) * ntot;
            out[O_NCS + i] = (float)c2;
        }
        double ent = 0.0;
        for (int i = tid; i < K_; i += 256) {
            double p = (double)cnt[i] / 32768.0;
            ent += -p * log(p + 1e-10);
        }
        for (int m = 32; m > 0; m >>= 1) ent += __shfl_xor(ent, m, 64);
        if ((tid & 63) == 0) redd[8 + (tid >> 6)] = ent;
        double ls = 0.0;
        for (int i = tid; i < N_; i += 256) ls += lossP[i];
        for (int m = 32; m > 0; m >>= 1) ls += __shfl_xor(ls, m, 64);
        if ((tid & 63) == 0) redd[16 + (tid >> 6)] = ls;
        __syncthreads();
        if (tid == 0) {
            double e = redd[8] + redd[9] + redd[10] + redd[11];
            double l = redd[16] + redd[17] + redd[18] + redd[19];
            out[O_PERP] = (float)exp(e);
            out[O_LOSS] = (float)(1.25 * l / 8388608.0);
        }
    }
}

extern "C" void kernel_launch(void* const* d_in, const int* in_sizes, int n_in,
                              void* d_out, int out_size, void* d_ws, size_t ws_size,
                              hipStream_t stream) {
    (void)in_sizes; (void)n_in; (void)out_size; (void)ws_size;
    const float* x      = (const float*)d_in[0];
    const float* w      = (const float*)d_in[1];
    const float* ema_w  = (const float*)d_in[2];
    const float* ema_cs = (const float*)d_in[3];
    const float* g      = (const float*)d_in[4];
    const float* bt     = (const float*)d_in[5];
    float* out = (float*)d_out;
    char* ws = (char*)d_ws;

    _Float16* fh = (_Float16*)(ws + OFF_FH);
    _Float16* wh = (_Float16*)(ws + OFF_WH);
    double* Bw   = (double*)(ws + OFF_BW);
    float*  Bwf  = (float*)(ws + OFF_BWF);
    double* samp = (double*)(ws + OFF_SAMP);
    int*    idxf = (int*)(ws + OFF_IDXF);
    int*    enc  = (int*)(ws + OFF_ENC);
    unsigned* cnt = (unsigned*)(ws + OFF_CNT);
    unsigned* slowC = (unsigned*)(ws + OFF_SLOWC);
    int*    slowL = (int*)(ws + OFF_SLOWL);
    double* lossP = (double*)(ws + OFF_LOSSP);

    (void)hipMemsetAsync(ws + OFF_CNT, 0, 4160, stream);   // cnt + slowC

    k_pre<<<N_ / 4 + K_ / 4, 256, 0, stream>>>(x, g, bt, fh, w, Bw, Bwf, wh);
    k_phase1<<<512, 64, 0, stream>>>(fh, wh, Bwf, out);   // top-2 partials in out-Q
    k_phase2<<<N_ / 4, 256, 0, stream>>>(x, g, bt, w, Bw, out, samp, idxf, slowC, slowL);
    k_slow<<<2048, 256, 0, stream>>>(x, g, bt, w, Bw, slowL, slowC, samp, idxf);
    k_sort<<<B_, 1024, 0, stream>>>(samp, idxf, enc);
    k_gather<<<N_ / 4, 256, 0, stream>>>(x, w, enc, out, cnt, lossP);
    k_post<<<K_ + 1, 256, 0, stream>>>(cnt, ema_cs, lossP, enc, x, ema_w, out);
}